// Round 11
// baseline (182.403 us; speedup 1.0000x reference)
//
#include <hip/hip_runtime.h>
#include <math.h>

// ---------------------------------------------------------------------------
// B=16, N=1024, C=256, SIZE=(512,640), STRIDE=8 -> H0=64, W0=80, P_TOK=5120
// NHEAD=8, NLVL=4, NPTS=4, HD=32, NUM_CLASSES=7
// pyramid: (64,80)(32,40)(16,20)(8,10); S_total=6800
// ---------------------------------------------------------------------------

namespace {

constexpr int kB = 16;
constexpr int kN = 1024;
constexpr int kC = 256;
constexpr int kNCLS = 7;
constexpr int kSTOT = 6800;

typedef __attribute__((ext_vector_type(8))) short short8;
typedef __attribute__((ext_vector_type(4))) float f32x4;

__device__ inline ushort f2bf(float f) {
  union { float f; unsigned u; } v; v.f = f;
  unsigned r = (v.u + 0x7fffu + ((v.u >> 16) & 1u)) >> 16;
  return (ushort)r;
}
__device__ inline float bf2f(ushort h) {
  union { unsigned u; float f; } v; v.u = ((unsigned)h) << 16;
  return v.f;
}

__device__ inline void gload16(const ushort* g, ushort* l) {
  __builtin_amdgcn_global_load_lds(
      (const __attribute__((address_space(1))) void*)g,
      (__attribute__((address_space(3))) void*)l, 16, 0, 0);
}

// ---------------- q_t cast ---------------------------------------------------
__global__ void cast_f2b_kernel(const float* __restrict__ in, ushort* __restrict__ out, int n4) {
  int i = blockIdx.x * 256 + threadIdx.x;
  if (i >= n4) return;
  float4 v = ((const float4*)in)[i];
  ((ushort4*)out)[i] = make_ushort4(f2bf(v.x), f2bf(v.y), f2bf(v.z), f2bf(v.w));
}

// ---------------- fused: h_t cast->L0 bf16 + 2x2 pool->L1 bf16 --------------
__global__ void cast_pool_kernel(const float* __restrict__ h, ushort* __restrict__ fsc) {
  int i = blockIdx.x * 256 + threadIdx.x;
  if (i >= kB * 32 * 40 * 64) return;
  int cq = i & 63;
  int t = i >> 6;
  int x = t % 40; t /= 40;
  int y = t % 32; int b = t / 32;
  const float* base = h + (((size_t)b * 5120 + (2 * y) * 80 + 2 * x) << 8) + (cq << 2);
  float4 v00 = *(const float4*)(base);
  float4 v01 = *(const float4*)(base + 256);
  float4 v10 = *(const float4*)(base + 80 * 256);
  float4 v11 = *(const float4*)(base + 80 * 256 + 256);
  ushort* f0 = fsc + (((size_t)b * kSTOT + (2 * y) * 80 + 2 * x) << 8) + (cq << 2);
  *(ushort4*)(f0) = make_ushort4(f2bf(v00.x), f2bf(v00.y), f2bf(v00.z), f2bf(v00.w));
  *(ushort4*)(f0 + 256) = make_ushort4(f2bf(v01.x), f2bf(v01.y), f2bf(v01.z), f2bf(v01.w));
  *(ushort4*)(f0 + 80 * 256) = make_ushort4(f2bf(v10.x), f2bf(v10.y), f2bf(v10.z), f2bf(v10.w));
  *(ushort4*)(f0 + 80 * 256 + 256) =
      make_ushort4(f2bf(v11.x), f2bf(v11.y), f2bf(v11.z), f2bf(v11.w));
  float4 pv = make_float4(0.25f * (v00.x + v01.x + v10.x + v11.x),
                          0.25f * (v00.y + v01.y + v10.y + v11.y),
                          0.25f * (v00.z + v01.z + v10.z + v11.z),
                          0.25f * (v00.w + v01.w + v10.w + v11.w));
  ushort* f1 = fsc + (((size_t)b * kSTOT + 5120 + y * 40 + x) << 8) + (cq << 2);
  *(ushort4*)(f1) = make_ushort4(f2bf(pv.x), f2bf(pv.y), f2bf(pv.z), f2bf(pv.w));
}

__global__ void pool_b2b_kernel(const ushort* __restrict__ fin, ushort* __restrict__ fout,
                                int oh, int ow, int so_in, int so_out) {
  int idx = blockIdx.x * 256 + threadIdx.x;
  if (idx >= kB * oh * ow * kC) return;
  int c = idx & 255; int t = idx >> 8;
  int x = t % ow; t /= ow; int y = t % oh; int b = t / oh;
  int iw = ow * 2;
  const ushort* p = fin + (((size_t)b * kSTOT + so_in + y * 2 * iw + x * 2) << 8) + c;
  float s = 0.25f * (bf2f(p[0]) + bf2f(p[256]) + bf2f(p[iw * 256]) + bf2f(p[iw * 256 + 256]));
  fout[(((size_t)b * kSTOT + so_out + y * ow + x) << 8) + c] = f2bf(s);
}

// ---------------- all weight transposes in one launch -----------------------
__global__ void wtrans_all_kernel(const float* __restrict__ s0, const float* __restrict__ s1,
                                  const float* __restrict__ s2, const float* __restrict__ s3,
                                  const float* __restrict__ s4,
                                  ushort* __restrict__ d0, ushort* __restrict__ d1,
                                  ushort* __restrict__ d2, ushort* __restrict__ d3,
                                  ushort* __restrict__ d4) {
  __shared__ float t[32][33];
  const float* W; ushort* Wt; int K, N;
  switch (blockIdx.z) {
    case 0: W = s0; Wt = d0; K = 256; N = 256; break;
    case 1: W = s1; Wt = d1; K = 256; N = 256; break;
    case 2: W = s2; Wt = d2; K = 256; N = 128; break;
    case 3: W = s3; Wt = d3; K = 256; N = 256; break;
    default: W = s4; Wt = d4; K = 512; N = 256; break;
  }
  int nx = blockIdx.x << 5, ky = blockIdx.y << 5;
  if (nx >= N || ky >= K) return;
  int lx = threadIdx.x & 31, ly = threadIdx.x >> 5;
#pragma unroll
  for (int i = 0; i < 32; i += 8)
    t[ly + i][lx] = W[(size_t)(ky + ly + i) * N + nx + lx];
  __syncthreads();
#pragma unroll
  for (int i = 0; i < 32; i += 8)
    Wt[(size_t)(nx + ly + i) * K + ky + lx] = f2bf(t[lx][ly + i]);
}

// ---------------- bf16 MFMA GEMM, 128x128 tile (small-M GEMMs) --------------
template <int KTOT, bool SPLITK, int OMODE, bool RELU>
__global__ __launch_bounds__(256) void gemm_bf16_kernel(
    const ushort* __restrict__ A, const ushort* __restrict__ A2,
    const ushort* __restrict__ Wt, const float* __restrict__ bias,
    const float* __restrict__ bias2, void* __restrict__ Cout,
    void* __restrict__ Cout2, int ldc) {
  __shared__ ushort Asm[2][128 * 32];
  __shared__ ushort Bsm[2][128 * 32];
  const int tid = threadIdx.x;
  const int w = tid >> 6, l = tid & 63;
  const int bm = blockIdx.y << 7, bn = blockIdx.x << 7;
  const int wm = w >> 1, wn = w & 1;

  const int c0 = w * 2, c1 = w * 2 + 1;
  const int G0 = c0 * 64 + l, G1 = c1 * 64 + l;
  const int r0 = G0 >> 2, g0 = G0 & 3;
  const int r1 = G1 >> 2, g1 = G1 & 3;
  const int sz0 = (g0 ^ ((r0 >> 1) & 3)) << 3;
  const int sz1 = (g1 ^ ((r1 >> 1) & 3)) << 3;
  const int ak = SPLITK ? 256 : KTOT;
  const ushort* sA0 = A + (size_t)(bm + r0) * ak + sz0;
  const ushort* sA1 = A + (size_t)(bm + r1) * ak + sz1;
  const ushort* sA0b = SPLITK ? A2 + (size_t)(bm + r0) * 256 + sz0 : nullptr;
  const ushort* sA1b = SPLITK ? A2 + (size_t)(bm + r1) * 256 + sz1 : nullptr;
  const ushort* sB0 = Wt + (size_t)(bn + r0) * KTOT + sz0;
  const ushort* sB1 = Wt + (size_t)(bn + r1) * KTOT + sz1;

  const int e = l >> 4, rl = l & 15;
  int aoff[4], boff[4];
#pragma unroll
  for (int i = 0; i < 4; ++i) {
    int r = wm * 64 + i * 16 + rl;
    aoff[i] = r * 32 + ((e ^ ((r >> 1) & 3)) << 3);
    int rb = wn * 64 + i * 16 + rl;
    boff[i] = rb * 32 + ((e ^ ((rb >> 1) & 3)) << 3);
  }

  f32x4 acc[4][4];
#pragma unroll
  for (int i = 0; i < 4; ++i)
#pragma unroll
    for (int j = 0; j < 4; ++j) acc[i][j] = (f32x4){0.f, 0.f, 0.f, 0.f};

  auto stage = [&](int buf, int k0) {
    const ushort *a0, *a1;
    if (SPLITK && k0 >= 256) {
      a0 = sA0b + (k0 - 256);
      a1 = sA1b + (k0 - 256);
    } else {
      a0 = sA0 + k0;
      a1 = sA1 + k0;
    }
    gload16(a0, &Asm[buf][c0 * 512]);
    gload16(a1, &Asm[buf][c1 * 512]);
    gload16(sB0 + k0, &Bsm[buf][c0 * 512]);
    gload16(sB1 + k0, &Bsm[buf][c1 * 512]);
  };

  constexpr int nt = KTOT / 32;
  stage(0, 0);
  __syncthreads();
  for (int t = 0; t < nt; ++t) {
    const int cur = t & 1;
    if (t + 1 < nt) stage(cur ^ 1, (t + 1) * 32);
    short8 af[4], bfr[4];
#pragma unroll
    for (int i = 0; i < 4; ++i) af[i] = *(const short8*)&Asm[cur][aoff[i]];
#pragma unroll
    for (int j = 0; j < 4; ++j) bfr[j] = *(const short8*)&Bsm[cur][boff[j]];
    // swapped operands: acc[i][j] = (Wt-subtile j) x (A-subtile i)^T = C^T tile
#pragma unroll
    for (int i = 0; i < 4; ++i)
#pragma unroll
      for (int j = 0; j < 4; ++j)
        acc[i][j] = __builtin_amdgcn_mfma_f32_16x16x32_bf16(bfr[j], af[i], acc[i][j], 0, 0, 0);
    __syncthreads();
  }

  // epilogue (swapped layout): reg r = channel ch+r, lane&15 = spatial row
#pragma unroll
  for (int j = 0; j < 4; ++j) {
    int ch = bn + wn * 64 + j * 16 + e * 4;
    float4 b4;
    if (OMODE == 2)
      b4 = (ch < 256) ? *(const float4*)(bias + ch) : *(const float4*)(bias2 + ch - 256);
    else
      b4 = *(const float4*)(bias + ch);
    float bv[4] = {b4.x, b4.y, b4.z, b4.w};
#pragma unroll
    for (int i = 0; i < 4; ++i) {
      int sp = bm + wm * 64 + i * 16 + rl;
      float v[4];
#pragma unroll
      for (int r = 0; r < 4; ++r) {
        v[r] = acc[i][j][r] + bv[r];
        if (RELU) v[r] = fmaxf(v[r], 0.f);
      }
      if (OMODE == 0) {
        *(float4*)&((float*)Cout)[(size_t)sp * ldc + ch] = make_float4(v[0], v[1], v[2], v[3]);
      } else if (OMODE == 1) {
        *(ushort4*)&((ushort*)Cout)[(size_t)sp * ldc + ch] =
            make_ushort4(f2bf(v[0]), f2bf(v[1]), f2bf(v[2]), f2bf(v[3]));
      } else {
        if (ch < 256)
          *(float4*)&((float*)Cout)[(size_t)sp * 256 + ch] = make_float4(v[0], v[1], v[2], v[3]);
        else
          *(float4*)&((float*)Cout2)[(size_t)sp * 128 + (ch - 256)] =
              make_float4(v[0], v[1], v[2], v[3]);
      }
    }
  }
}

// ---------------- 256x128-tile GEMM for the big value GEMM ------------------
// K=256 fixed, A [M][256] bf16, Wt [256][256] bf16 -> C [M][256] bf16.
// 4 waves, each owns 128 rows x 64 cols (acc[8][4]); BK=32, dbuf (48 KB LDS).
// 2x the MFMA per barrier-stall and half the total stalls vs 128-tile —
// attacks the skinny-K barrier-drain serialization (MfmaUtil 10%, all idle).
__global__ __launch_bounds__(256) void gemm256_kernel(
    const ushort* __restrict__ A, const ushort* __restrict__ Wt,
    const float* __restrict__ bias, ushort* __restrict__ Cout) {
  __shared__ ushort Asm[2][256 * 32];  // 16 KB each
  __shared__ ushort Bsm[2][128 * 32];  //  8 KB each
  const int tid = threadIdx.x;
  const int w = tid >> 6, l = tid & 63;
  const int bm = blockIdx.y << 8, bn = blockIdx.x << 7;
  const int wm = w >> 1, wn = w & 1;

  // staging: A = 16 chunks of 1KB (wave w -> chunks 4w..4w+3),
  //          B = 8 chunks (wave w -> 2w..2w+1). granule G=c*64+l, row=G>>2,
  //          slot g=G&3, src col-granule = g ^ ((row>>1)&3); LDS dest linear.
  const ushort* sA[4];
  const ushort* sB[2];
#pragma unroll
  for (int k = 0; k < 4; ++k) {
    int G = (w * 4 + k) * 64 + l, r = G >> 2, g = G & 3;
    sA[k] = A + (size_t)(bm + r) * 256 + ((g ^ ((r >> 1) & 3)) << 3);
  }
#pragma unroll
  for (int k = 0; k < 2; ++k) {
    int G = (w * 2 + k) * 64 + l, r = G >> 2, g = G & 3;
    sB[k] = Wt + (size_t)(bn + r) * 256 + ((g ^ ((r >> 1) & 3)) << 3);
  }

  const int e = l >> 4, rl = l & 15;
  int aoff[8], boff[4];
#pragma unroll
  for (int i = 0; i < 8; ++i) {
    int r = wm * 128 + i * 16 + rl;
    aoff[i] = r * 32 + ((e ^ ((r >> 1) & 3)) << 3);
  }
#pragma unroll
  for (int j = 0; j < 4; ++j) {
    int rb = wn * 64 + j * 16 + rl;
    boff[j] = rb * 32 + ((e ^ ((rb >> 1) & 3)) << 3);
  }

  f32x4 acc[8][4];
#pragma unroll
  for (int i = 0; i < 8; ++i)
#pragma unroll
    for (int j = 0; j < 4; ++j) acc[i][j] = (f32x4){0.f, 0.f, 0.f, 0.f};

  auto stage = [&](int buf, int k0) {
#pragma unroll
    for (int k = 0; k < 4; ++k) gload16(sA[k] + k0, &Asm[buf][(w * 4 + k) * 512]);
#pragma unroll
    for (int k = 0; k < 2; ++k) gload16(sB[k] + k0, &Bsm[buf][(w * 2 + k) * 512]);
  };

  stage(0, 0);
  __syncthreads();
  for (int t = 0; t < 8; ++t) {
    const int cur = t & 1;
    if (t < 7) stage(cur ^ 1, (t + 1) * 32);
    short8 af[8], bfr[4];
#pragma unroll
    for (int i = 0; i < 8; ++i) af[i] = *(const short8*)&Asm[cur][aoff[i]];
#pragma unroll
    for (int j = 0; j < 4; ++j) bfr[j] = *(const short8*)&Bsm[cur][boff[j]];
    // swapped operands -> reg dim = 4 contiguous channels (vector stores)
#pragma unroll
    for (int i = 0; i < 8; ++i)
#pragma unroll
      for (int j = 0; j < 4; ++j)
        acc[i][j] = __builtin_amdgcn_mfma_f32_16x16x32_bf16(bfr[j], af[i], acc[i][j], 0, 0, 0);
    __syncthreads();
  }

#pragma unroll
  for (int j = 0; j < 4; ++j) {
    int ch = bn + wn * 64 + j * 16 + e * 4;
    float4 b4 = *(const float4*)(bias + ch);
    float bv[4] = {b4.x, b4.y, b4.z, b4.w};
#pragma unroll
    for (int i = 0; i < 8; ++i) {
      int sp = bm + wm * 128 + i * 16 + rl;
      float v[4];
#pragma unroll
      for (int r = 0; r < 4; ++r) v[r] = acc[i][j][r] + bv[r];
      *(ushort4*)&Cout[(size_t)sp * 256 + ch] =
          make_ushort4(f2bf(v[0]), f2bf(v[1]), f2bf(v[2]), f2bf(v[3]));
    }
  }
}

// ---------------- deformable sampling, softmax fused ------------------------
// 4-wave blocks; wave serves TWO points; 32 lanes per point (ushort8 gathers).
// NO launch_bounds (r2/r4 spill regressions). Outer level loop `#pragma
// unroll 1` keeps only one level's 16 gathers in flight (natural VGPR ~130).
__global__ void deform_kernel(
    const ushort* __restrict__ value, const float* __restrict__ off,
    const float* __restrict__ attnl, const float* __restrict__ p_head,
    ushort* __restrict__ samp) {
  int blk = (int)blockIdx.x;                // 2048 blocks
  int sw = (blk & 7) * 256 + (blk >> 3);    // bijective XCD swizzle (2048 = 8*256)
  int wvi = (sw << 2) + (threadIdx.x >> 6); // wave id in [0,8192)
  int l = threadIdx.x & 63;
  int nq = l >> 5;
  int lh = l & 31;
  int h = lh >> 2;
  int pt = wvi * 2 + nq;
  int b = pt >> 10;
  size_t bn = (size_t)pt;

  float ph = (lh < 2) ? p_head[bn * 2 + lh] : 0.f;
  float px = __shfl(ph, (nq << 5) + 0, 64) * (1.0f / 640.0f);
  float py = __shfl(ph, (nq << 5) + 1, 64) * (1.0f / 512.0f);
  px = fminf(fmaxf(px, 0.f), 1.f);
  py = fminf(fmaxf(py, 0.f), 1.f);

  const float4* offp = (const float4*)(off + (bn << 8));
  float4 ofv0 = offp[2 * lh];
  float4 ofv1 = offp[2 * lh + 1];
  float4 atv = ((const float4*)(attnl + (bn << 7)))[lh];

  float m = fmaxf(fmaxf(atv.x, atv.y), fmaxf(atv.z, atv.w));
  m = fmaxf(m, __shfl_xor(m, 1, 64));
  m = fmaxf(m, __shfl_xor(m, 2, 64));
  float e0 = expf(atv.x - m), e1 = expf(atv.y - m);
  float e2 = expf(atv.z - m), e3 = expf(atv.w - m);
  float s = e0 + e1 + e2 + e3;
  s += __shfl_xor(s, 1, 64);
  s += __shfl_xor(s, 2, 64);
  float inv = 1.f / s;
  atv = make_float4(e0 * inv, e1 * inv, e2 * inv, e3 * inv);

  float acc[8];
#pragma unroll
  for (int i = 0; i < 8; ++i) acc[i] = 0.f;
  const ushort* vbb = value + (((size_t)b * kSTOT) << 8) + (lh << 3);

#pragma unroll 1
  for (int lv = 0; lv < 4; ++lv) {
    const int Wl = 80 >> lv, Hl = 64 >> lv;
    const int offL = (lv == 0) ? 0 : (lv == 1) ? 5120 : (lv == 2) ? 6400 : 6720;
    const ushort* vb = vbb + (((size_t)offL) << 8);
    const int src = (nq << 5) + (h << 2) + lv;
    const float fx = px * (float)Wl - 0.5f;
    const float fy = py * (float)Hl - 0.5f;
#pragma unroll
    for (int pp = 0; pp < 4; ++pp) {
      float sx, sy;
      if ((pp >> 1) == 0) {
        sx = (pp & 1) ? ofv0.z : ofv0.x;
        sy = (pp & 1) ? ofv0.w : ofv0.y;
      } else {
        sx = (pp & 1) ? ofv1.z : ofv1.x;
        sy = (pp & 1) ? ofv1.w : ofv1.y;
      }
      float ox = __shfl(sx, src, 64);
      float oy = __shfl(sy, src, 64);
      float sa = pp == 0 ? atv.x : pp == 1 ? atv.y : pp == 2 ? atv.z : atv.w;
      float aw = __shfl(sa, src, 64);

      float xx = fx + ox;
      float yy = fy + oy;
      float x0f = floorf(xx), y0f = floorf(yy);
      float wx = xx - x0f, wy = yy - y0f;
      int x0 = (int)x0f, y0 = (int)y0f;
      float w00 = (1.f - wx) * (1.f - wy) * aw;
      float w01 = wx * (1.f - wy) * aw;
      float w10 = (1.f - wx) * wy * aw;
      float w11 = wx * wy * aw;
      auto corner = [&](int xi, int yi, float wgt) {
        bool valid = (xi >= 0) && (xi < Wl) && (yi >= 0) && (yi < Hl);
        int xc = xi < 0 ? 0 : (xi > Wl - 1 ? Wl - 1 : xi);
        int yc = yi < 0 ? 0 : (yi > Hl - 1 ? Hl - 1 : yi);
        short8 d = *(const short8*)(vb + (((size_t)(yc * Wl + xc)) << 8));
        float wg = valid ? wgt : 0.f;
#pragma unroll
        for (int i = 0; i < 8; ++i) acc[i] = fmaf(wg, bf2f((ushort)d[i]), acc[i]);
      };
      corner(x0, y0, w00);
      corner(x0 + 1, y0, w01);
      corner(x0, y0 + 1, w10);
      corner(x0 + 1, y0 + 1, w11);
    }
  }
  ushort o[8];
#pragma unroll
  for (int i = 0; i < 8; ++i) o[i] = f2bf(acc[i]);
  *(short8*)(samp + (bn << 8) + (lh << 3)) =
      (short8){(short)o[0], (short)o[1], (short)o[2], (short)o[3],
               (short)o[4], (short)o[5], (short)o[6], (short)o[7]};
}

// ---------------- final head: (B*N,256)@(256,7)+b, one wave per row ---------
__global__ void head_kernel(const float* __restrict__ hid, const float* __restrict__ W2,
                            const float* __restrict__ b2, float* __restrict__ outp) {
  int gid = blockIdx.x * 256 + threadIdx.x;
  int wave = gid >> 6;
  int lane = threadIdx.x & 63;
  if (wave >= kB * kN) return;
  const float* hrow = hid + ((size_t)wave << 8);
  float acc[kNCLS];
#pragma unroll
  for (int j = 0; j < kNCLS; ++j) acc[j] = 0.f;
  for (int k = lane; k < kC; k += 64) {
    float hv = hrow[k];
    const float* wr = W2 + k * kNCLS;
#pragma unroll
    for (int j = 0; j < kNCLS; ++j) acc[j] = fmaf(hv, wr[j], acc[j]);
  }
#pragma unroll
  for (int m = 32; m > 0; m >>= 1) {
#pragma unroll
    for (int j = 0; j < kNCLS; ++j) acc[j] += __shfl_xor(acc[j], m);
  }
  float r = 0.f;
#pragma unroll
  for (int j = 0; j < kNCLS; ++j)
    if (lane == j) r = acc[j] + b2[j];
  if (lane < kNCLS) outp[(size_t)wave * kNCLS + lane] = r;
}

}  // namespace

extern "C" void kernel_launch(void* const* d_in, const int* in_sizes, int n_in,
                              void* d_out, int out_size, void* d_ws, size_t ws_size,
                              hipStream_t stream) {
  const float* q_t    = (const float*)d_in[0];
  const float* h_t    = (const float*)d_in[1];
  const float* p_head = (const float*)d_in[2];
  const float* W_off  = (const float*)d_in[3];
  const float* b_off  = (const float*)d_in[4];
  const float* W_attn = (const float*)d_in[5];
  const float* b_attn = (const float*)d_in[6];
  const float* W_v    = (const float*)d_in[7];
  const float* b_v    = (const float*)d_in[8];
  const float* W_o    = (const float*)d_in[9];
  const float* b_o    = (const float*)d_in[10];
  const float* W_p1   = (const float*)d_in[11];
  const float* b_p1   = (const float*)d_in[12];
  const float* W_p2   = (const float*)d_in[13];
  const float* b_p2   = (const float*)d_in[14];
  float* out = (float*)d_out;
  char* wsb = (char*)d_ws;

  ushort* fsc   = (ushort*)(wsb + 0);            // 55,705,600
  ushort* value = (ushort*)(wsb + 55705600);     // 55,705,600
  ushort* q_bf  = (ushort*)(wsb + 111411200);    //  8,388,608
  float*  offb  = (float*)(wsb + 119799808);     // 16,777,216
  float*  attnl = (float*)(wsb + 136577024);     //  8,388,608 (raw logits)
  ushort* samp  = (ushort*)(wsb + 144965632);    //  8,388,608
  ushort* qloc  = (ushort*)(wsb + 153354240);    //  8,388,608 (bf16)
  float*  hid   = (float*)(wsb + 161742848);     // 16,777,216
  ushort* wtp   = (ushort*)(wsb + 178520064);    //    720,896
  ushort* Wt_v  = wtp;                  // [256][256]
  ushort* Wt_oa = wtp + 65536;          // [384][256]
  ushort* Wt_o  = wtp + 163840;         // [256][256]
  ushort* Wt_p1 = wtp + 229376;         // [256][512]

  cast_f2b_kernel<<<4096, 256, 0, stream>>>(q_t, q_bf, kB * kN * 64);
  cast_pool_kernel<<<5120, 256, 0, stream>>>(h_t, fsc);
  pool_b2b_kernel<<<5120, 256, 0, stream>>>(fsc, fsc, 16, 20, 5120, 6400);
  pool_b2b_kernel<<<1280, 256, 0, stream>>>(fsc, fsc, 8, 10, 6400, 6720);

  wtrans_all_kernel<<<dim3(8, 16, 5), 256, 0, stream>>>(
      W_v, W_off, W_attn, W_o, W_p1,
      Wt_v, Wt_oa, Wt_oa + 65536, Wt_o, Wt_p1);

  // value = f_scales @ W_v + b_v  (M=108800 = 425*256)
  gemm256_kernel<<<dim3(2, 425), 256, 0, stream>>>(fsc, Wt_v, b_v, value);

  gemm_bf16_kernel<256, false, 2, false><<<dim3(3, 128), 256, 0, stream>>>(
      q_bf, nullptr, Wt_oa, b_off, b_attn, offb, attnl, 256);

  deform_kernel<<<2048, 256, 0, stream>>>(value, offb, attnl, p_head, samp);

  gemm_bf16_kernel<256, false, 1, false><<<dim3(2, 128), 256, 0, stream>>>(
      samp, nullptr, Wt_o, b_o, nullptr, qloc, nullptr, 256);

  gemm_bf16_kernel<512, true, 0, true><<<dim3(2, 128), 256, 0, stream>>>(
      q_bf, qloc, Wt_p1, b_p1, nullptr, hid, nullptr, 256);

  head_kernel<<<4096, 256, 0, stream>>>(hid, W_p2, b_p2, out);
}

// Round 12
// 152.120 us; speedup vs baseline: 1.1991x; 1.1991x over previous
//
#include <hip/hip_runtime.h>
#include <math.h>

// ---------------------------------------------------------------------------
// B=16, N=1024, C=256, SIZE=(512,640), STRIDE=8 -> H0=64, W0=80, P_TOK=5120
// NHEAD=8, NLVL=4, NPTS=4, HD=32, NUM_CLASSES=7
// pyramid: (64,80)(32,40)(16,20)(8,10); S_total=6800
// Key identity used below: pool2x2 is linear => pool(f)@W_v + b = pool(f@W_v + b),
// so the value pyramid is built AFTER the projection (h_t read exactly once).
// ---------------------------------------------------------------------------

namespace {

constexpr int kB = 16;
constexpr int kN = 1024;
constexpr int kC = 256;
constexpr int kNCLS = 7;
constexpr int kSTOT = 6800;

typedef __attribute__((ext_vector_type(8))) short short8;
typedef __attribute__((ext_vector_type(4))) float f32x4;

__device__ inline ushort f2bf(float f) {
  union { float f; unsigned u; } v; v.f = f;
  unsigned r = (v.u + 0x7fffu + ((v.u >> 16) & 1u)) >> 16;
  return (ushort)r;
}
__device__ inline float bf2f(ushort h) {
  union { unsigned u; float f; } v; v.u = ((unsigned)h) << 16;
  return v.f;
}

__device__ inline void gload16(const ushort* g, ushort* l) {
  __builtin_amdgcn_global_load_lds(
      (const __attribute__((address_space(1))) void*)g,
      (__attribute__((address_space(3))) void*)l, 16, 0, 0);
}

// ---------------- q_t cast ---------------------------------------------------
__global__ void cast_f2b_kernel(const float* __restrict__ in, ushort* __restrict__ out, int n4) {
  int i = blockIdx.x * 256 + threadIdx.x;
  if (i >= n4) return;
  float4 v = ((const float4*)in)[i];
  ((ushort4*)out)[i] = make_ushort4(f2bf(v.x), f2bf(v.y), f2bf(v.z), f2bf(v.w));
}

// ---------------- bf16 2x2 pool on the value pyramid ------------------------
__global__ void pool_b2b_kernel(const ushort* __restrict__ fin, ushort* __restrict__ fout,
                                int oh, int ow, int so_in, int so_out) {
  int idx = blockIdx.x * 256 + threadIdx.x;
  if (idx >= kB * oh * ow * kC) return;
  int c = idx & 255; int t = idx >> 8;
  int x = t % ow; t /= ow; int y = t % oh; int b = t / oh;
  int iw = ow * 2;
  const ushort* p = fin + (((size_t)b * kSTOT + so_in + y * 2 * iw + x * 2) << 8) + c;
  float s = 0.25f * (bf2f(p[0]) + bf2f(p[256]) + bf2f(p[iw * 256]) + bf2f(p[iw * 256 + 256]));
  fout[(((size_t)b * kSTOT + so_out + y * ow + x) << 8) + c] = f2bf(s);
}

// ---------------- all weight transposes in one launch -----------------------
__global__ void wtrans_all_kernel(const float* __restrict__ s0, const float* __restrict__ s1,
                                  const float* __restrict__ s2, const float* __restrict__ s3,
                                  const float* __restrict__ s4,
                                  ushort* __restrict__ d0, ushort* __restrict__ d1,
                                  ushort* __restrict__ d2, ushort* __restrict__ d3,
                                  ushort* __restrict__ d4) {
  __shared__ float t[32][33];
  const float* W; ushort* Wt; int K, N;
  switch (blockIdx.z) {
    case 0: W = s0; Wt = d0; K = 256; N = 256; break;
    case 1: W = s1; Wt = d1; K = 256; N = 256; break;
    case 2: W = s2; Wt = d2; K = 256; N = 128; break;
    case 3: W = s3; Wt = d3; K = 256; N = 256; break;
    default: W = s4; Wt = d4; K = 512; N = 256; break;
  }
  int nx = blockIdx.x << 5, ky = blockIdx.y << 5;
  if (nx >= N || ky >= K) return;
  int lx = threadIdx.x & 31, ly = threadIdx.x >> 5;
#pragma unroll
  for (int i = 0; i < 32; i += 8)
    t[ly + i][lx] = W[(size_t)(ky + ly + i) * N + nx + lx];
  __syncthreads();
#pragma unroll
  for (int i = 0; i < 32; i += 8)
    Wt[(size_t)(nx + ly + i) * K + ky + lx] = f2bf(t[lx][ly + i]);
}

// ---------------- bf16 MFMA GEMM, 128x128 tile (small-M GEMMs) --------------
template <int KTOT, bool SPLITK, int OMODE, bool RELU>
__global__ __launch_bounds__(256) void gemm_bf16_kernel(
    const ushort* __restrict__ A, const ushort* __restrict__ A2,
    const ushort* __restrict__ Wt, const float* __restrict__ bias,
    const float* __restrict__ bias2, void* __restrict__ Cout,
    void* __restrict__ Cout2, int ldc) {
  __shared__ ushort Asm[2][128 * 32];
  __shared__ ushort Bsm[2][128 * 32];
  const int tid = threadIdx.x;
  const int w = tid >> 6, l = tid & 63;
  const int bm = blockIdx.y << 7, bn = blockIdx.x << 7;
  const int wm = w >> 1, wn = w & 1;

  const int c0 = w * 2, c1 = w * 2 + 1;
  const int G0 = c0 * 64 + l, G1 = c1 * 64 + l;
  const int r0 = G0 >> 2, g0 = G0 & 3;
  const int r1 = G1 >> 2, g1 = G1 & 3;
  const int sz0 = (g0 ^ ((r0 >> 1) & 3)) << 3;
  const int sz1 = (g1 ^ ((r1 >> 1) & 3)) << 3;
  const int ak = SPLITK ? 256 : KTOT;
  const ushort* sA0 = A + (size_t)(bm + r0) * ak + sz0;
  const ushort* sA1 = A + (size_t)(bm + r1) * ak + sz1;
  const ushort* sA0b = SPLITK ? A2 + (size_t)(bm + r0) * 256 + sz0 : nullptr;
  const ushort* sA1b = SPLITK ? A2 + (size_t)(bm + r1) * 256 + sz1 : nullptr;
  const ushort* sB0 = Wt + (size_t)(bn + r0) * KTOT + sz0;
  const ushort* sB1 = Wt + (size_t)(bn + r1) * KTOT + sz1;

  const int e = l >> 4, rl = l & 15;
  int aoff[4], boff[4];
#pragma unroll
  for (int i = 0; i < 4; ++i) {
    int r = wm * 64 + i * 16 + rl;
    aoff[i] = r * 32 + ((e ^ ((r >> 1) & 3)) << 3);
    int rb = wn * 64 + i * 16 + rl;
    boff[i] = rb * 32 + ((e ^ ((rb >> 1) & 3)) << 3);
  }

  f32x4 acc[4][4];
#pragma unroll
  for (int i = 0; i < 4; ++i)
#pragma unroll
    for (int j = 0; j < 4; ++j) acc[i][j] = (f32x4){0.f, 0.f, 0.f, 0.f};

  auto stage = [&](int buf, int k0) {
    const ushort *a0, *a1;
    if (SPLITK && k0 >= 256) {
      a0 = sA0b + (k0 - 256);
      a1 = sA1b + (k0 - 256);
    } else {
      a0 = sA0 + k0;
      a1 = sA1 + k0;
    }
    gload16(a0, &Asm[buf][c0 * 512]);
    gload16(a1, &Asm[buf][c1 * 512]);
    gload16(sB0 + k0, &Bsm[buf][c0 * 512]);
    gload16(sB1 + k0, &Bsm[buf][c1 * 512]);
  };

  constexpr int nt = KTOT / 32;
  stage(0, 0);
  __syncthreads();
  for (int t = 0; t < nt; ++t) {
    const int cur = t & 1;
    if (t + 1 < nt) stage(cur ^ 1, (t + 1) * 32);
    short8 af[4], bfr[4];
#pragma unroll
    for (int i = 0; i < 4; ++i) af[i] = *(const short8*)&Asm[cur][aoff[i]];
#pragma unroll
    for (int j = 0; j < 4; ++j) bfr[j] = *(const short8*)&Bsm[cur][boff[j]];
    // swapped operands: acc[i][j] = (Wt-subtile j) x (A-subtile i)^T = C^T tile
#pragma unroll
    for (int i = 0; i < 4; ++i)
#pragma unroll
      for (int j = 0; j < 4; ++j)
        acc[i][j] = __builtin_amdgcn_mfma_f32_16x16x32_bf16(bfr[j], af[i], acc[i][j], 0, 0, 0);
    __syncthreads();
  }

  // epilogue (swapped layout): reg r = channel ch+r, lane&15 = spatial row
#pragma unroll
  for (int j = 0; j < 4; ++j) {
    int ch = bn + wn * 64 + j * 16 + e * 4;
    float4 b4;
    if (OMODE == 2)
      b4 = (ch < 256) ? *(const float4*)(bias + ch) : *(const float4*)(bias2 + ch - 256);
    else
      b4 = *(const float4*)(bias + ch);
    float bv[4] = {b4.x, b4.y, b4.z, b4.w};
#pragma unroll
    for (int i = 0; i < 4; ++i) {
      int sp = bm + wm * 64 + i * 16 + rl;
      float v[4];
#pragma unroll
      for (int r = 0; r < 4; ++r) {
        v[r] = acc[i][j][r] + bv[r];
        if (RELU) v[r] = fmaxf(v[r], 0.f);
      }
      if (OMODE == 0) {
        *(float4*)&((float*)Cout)[(size_t)sp * ldc + ch] = make_float4(v[0], v[1], v[2], v[3]);
      } else if (OMODE == 1) {
        *(ushort4*)&((ushort*)Cout)[(size_t)sp * ldc + ch] =
            make_ushort4(f2bf(v[0]), f2bf(v[1]), f2bf(v[2]), f2bf(v[3]));
      } else {
        if (ch < 256)
          *(float4*)&((float*)Cout)[(size_t)sp * 256 + ch] = make_float4(v[0], v[1], v[2], v[3]);
        else
          *(float4*)&((float*)Cout2)[(size_t)sp * 128 + (ch - 256)] =
              make_float4(v[0], v[1], v[2], v[3]);
      }
    }
  }
}

// ---------------- fp32-A GEMM: value_L0 = h_t @ W_v + b_v -------------------
// A = h_t fp32 [81920][256] read ONCE (no fsc roundtrip); A reg-staged with
// on-the-fly bf16 convert (T14 split: loads issued before MFMA, cvt+ds_write
// after). B (bf16 Wt) via global_load_lds. 128x128 tile, BK=32, dbuf, 32KB LDS.
// Output remapped to value's 6800-stride layout (row-tiles never cross batch:
// 5120/128 = 40 exact).
__global__ __launch_bounds__(256) void gemm_f32a_kernel(
    const float* __restrict__ A, const ushort* __restrict__ Wt,
    const float* __restrict__ bias, ushort* __restrict__ Cout) {
  __shared__ ushort Asm[2][128 * 32];
  __shared__ ushort Bsm[2][128 * 32];
  const int tid = threadIdx.x;
  const int w = tid >> 6, l = tid & 63;
  const int by = blockIdx.y;
  const int bn = blockIdx.x << 7;
  const int bm = by << 7;
  const int wm = w >> 1, wn = w & 1;

  // A staging: thread -> (row ar, k-half ah); 16 floats -> 16 bf16 -> 2 b128
  const int ar = tid >> 1, ah = tid & 1;
  const float* aSrc = A + (size_t)(bm + ar) * 256 + ah * 16;
  const int s_ar = (ar >> 1) & 3;
  const int ad0 = ar * 32 + (((2 * ah + 0) ^ s_ar) << 3);  // ushort offsets
  const int ad1 = ar * 32 + (((2 * ah + 1) ^ s_ar) << 3);

  // B staging (gload16): 8 chunks of 1KB over 4 waves
  const int c0 = w * 2, c1 = w * 2 + 1;
  const int G0 = c0 * 64 + l, G1 = c1 * 64 + l;
  const int r0 = G0 >> 2, g0 = G0 & 3;
  const int r1 = G1 >> 2, g1 = G1 & 3;
  const ushort* sB0 = Wt + (size_t)(bn + r0) * 256 + ((g0 ^ ((r0 >> 1) & 3)) << 3);
  const ushort* sB1 = Wt + (size_t)(bn + r1) * 256 + ((g1 ^ ((r1 >> 1) & 3)) << 3);

  const int e = l >> 4, rl = l & 15;
  int aoff[4], boff[4];
#pragma unroll
  for (int i = 0; i < 4; ++i) {
    int r = wm * 64 + i * 16 + rl;
    aoff[i] = r * 32 + ((e ^ ((r >> 1) & 3)) << 3);
    int rb = wn * 64 + i * 16 + rl;
    boff[i] = rb * 32 + ((e ^ ((rb >> 1) & 3)) << 3);
  }

  f32x4 acc[4][4];
#pragma unroll
  for (int i = 0; i < 4; ++i)
#pragma unroll
    for (int j = 0; j < 4; ++j) acc[i][j] = (f32x4){0.f, 0.f, 0.f, 0.f};

  float4 av[4];
  auto loadA = [&](int k0) {
#pragma unroll
    for (int q = 0; q < 4; ++q) av[q] = *(const float4*)(aSrc + k0 + 4 * q);
  };
  auto writeA = [&](int buf) {
    ushort u[16];
#pragma unroll
    for (int q = 0; q < 4; ++q) {
      u[4 * q + 0] = f2bf(av[q].x);
      u[4 * q + 1] = f2bf(av[q].y);
      u[4 * q + 2] = f2bf(av[q].z);
      u[4 * q + 3] = f2bf(av[q].w);
    }
    *(short8*)&Asm[buf][ad0] =
        (short8){(short)u[0], (short)u[1], (short)u[2], (short)u[3],
                 (short)u[4], (short)u[5], (short)u[6], (short)u[7]};
    *(short8*)&Asm[buf][ad1] =
        (short8){(short)u[8], (short)u[9], (short)u[10], (short)u[11],
                 (short)u[12], (short)u[13], (short)u[14], (short)u[15]};
  };
  auto stageB = [&](int buf, int k0) {
    gload16(sB0 + k0, &Bsm[buf][c0 * 512]);
    gload16(sB1 + k0, &Bsm[buf][c1 * 512]);
  };

  loadA(0);
  stageB(0, 0);
  writeA(0);
  __syncthreads();
  for (int t = 0; t < 8; ++t) {
    const int cur = t & 1;
    if (t < 7) {
      loadA((t + 1) * 32);      // issue early: HBM latency hides under MFMAs
      stageB(cur ^ 1, (t + 1) * 32);
    }
    short8 af[4], bfr[4];
#pragma unroll
    for (int i = 0; i < 4; ++i) af[i] = *(const short8*)&Asm[cur][aoff[i]];
#pragma unroll
    for (int j = 0; j < 4; ++j) bfr[j] = *(const short8*)&Bsm[cur][boff[j]];
#pragma unroll
    for (int i = 0; i < 4; ++i)
#pragma unroll
      for (int j = 0; j < 4; ++j)
        acc[i][j] = __builtin_amdgcn_mfma_f32_16x16x32_bf16(bfr[j], af[i], acc[i][j], 0, 0, 0);
    if (t < 7) writeA(cur ^ 1);  // cvt + ds_write after compute
    __syncthreads();
  }

  // epilogue (swapped layout) into value's 6800-stride L0 region
  const int b = by / 40;
  const int sb = (by - b * 40) << 7;
  ushort* outB = Cout + (((size_t)(b * 6800 + sb)) << 8);
#pragma unroll
  for (int j = 0; j < 4; ++j) {
    int ch = bn + wn * 64 + j * 16 + e * 4;
    float4 b4 = *(const float4*)(bias + ch);
    float bv[4] = {b4.x, b4.y, b4.z, b4.w};
#pragma unroll
    for (int i = 0; i < 4; ++i) {
      int sp = wm * 64 + i * 16 + rl;
      float v[4];
#pragma unroll
      for (int r = 0; r < 4; ++r) v[r] = acc[i][j][r] + bv[r];
      *(ushort4*)&outB[(size_t)sp * 256 + ch] =
          make_ushort4(f2bf(v[0]), f2bf(v[1]), f2bf(v[2]), f2bf(v[3]));
    }
  }
}

// ---------------- deformable sampling, softmax fused ------------------------
// 4-wave blocks; wave serves TWO points; 32 lanes per point (ushort8 gathers).
// NO launch_bounds (r2/r4 spill regressions). Outer level loop `#pragma
// unroll 1` keeps only one level's 16 gathers in flight (natural VGPR ~130).
__global__ void deform_kernel(
    const ushort* __restrict__ value, const float* __restrict__ off,
    const float* __restrict__ attnl, const float* __restrict__ p_head,
    ushort* __restrict__ samp) {
  int blk = (int)blockIdx.x;                // 2048 blocks
  int sw = (blk & 7) * 256 + (blk >> 3);    // bijective XCD swizzle (2048 = 8*256)
  int wvi = (sw << 2) + (threadIdx.x >> 6); // wave id in [0,8192)
  int l = threadIdx.x & 63;
  int nq = l >> 5;
  int lh = l & 31;
  int h = lh >> 2;
  int pt = wvi * 2 + nq;
  int b = pt >> 10;
  size_t bn = (size_t)pt;

  float ph = (lh < 2) ? p_head[bn * 2 + lh] : 0.f;
  float px = __shfl(ph, (nq << 5) + 0, 64) * (1.0f / 640.0f);
  float py = __shfl(ph, (nq << 5) + 1, 64) * (1.0f / 512.0f);
  px = fminf(fmaxf(px, 0.f), 1.f);
  py = fminf(fmaxf(py, 0.f), 1.f);

  const float4* offp = (const float4*)(off + (bn << 8));
  float4 ofv0 = offp[2 * lh];
  float4 ofv1 = offp[2 * lh + 1];
  float4 atv = ((const float4*)(attnl + (bn << 7)))[lh];

  float m = fmaxf(fmaxf(atv.x, atv.y), fmaxf(atv.z, atv.w));
  m = fmaxf(m, __shfl_xor(m, 1, 64));
  m = fmaxf(m, __shfl_xor(m, 2, 64));
  float e0 = expf(atv.x - m), e1 = expf(atv.y - m);
  float e2 = expf(atv.z - m), e3 = expf(atv.w - m);
  float s = e0 + e1 + e2 + e3;
  s += __shfl_xor(s, 1, 64);
  s += __shfl_xor(s, 2, 64);
  float inv = 1.f / s;
  atv = make_float4(e0 * inv, e1 * inv, e2 * inv, e3 * inv);

  float acc[8];
#pragma unroll
  for (int i = 0; i < 8; ++i) acc[i] = 0.f;
  const ushort* vbb = value + (((size_t)b * kSTOT) << 8) + (lh << 3);

#pragma unroll 1
  for (int lv = 0; lv < 4; ++lv) {
    const int Wl = 80 >> lv, Hl = 64 >> lv;
    const int offL = (lv == 0) ? 0 : (lv == 1) ? 5120 : (lv == 2) ? 6400 : 6720;
    const ushort* vb = vbb + (((size_t)offL) << 8);
    const int src = (nq << 5) + (h << 2) + lv;
    const float fx = px * (float)Wl - 0.5f;
    const float fy = py * (float)Hl - 0.5f;
#pragma unroll
    for (int pp = 0; pp < 4; ++pp) {
      float sx, sy;
      if ((pp >> 1) == 0) {
        sx = (pp & 1) ? ofv0.z : ofv0.x;
        sy = (pp & 1) ? ofv0.w : ofv0.y;
      } else {
        sx = (pp & 1) ? ofv1.z : ofv1.x;
        sy = (pp & 1) ? ofv1.w : ofv1.y;
      }
      float ox = __shfl(sx, src, 64);
      float oy = __shfl(sy, src, 64);
      float sa = pp == 0 ? atv.x : pp == 1 ? atv.y : pp == 2 ? atv.z : atv.w;
      float aw = __shfl(sa, src, 64);

      float xx = fx + ox;
      float yy = fy + oy;
      float x0f = floorf(xx), y0f = floorf(yy);
      float wx = xx - x0f, wy = yy - y0f;
      int x0 = (int)x0f, y0 = (int)y0f;
      float w00 = (1.f - wx) * (1.f - wy) * aw;
      float w01 = wx * (1.f - wy) * aw;
      float w10 = (1.f - wx) * wy * aw;
      float w11 = wx * wy * aw;
      auto corner = [&](int xi, int yi, float wgt) {
        bool valid = (xi >= 0) && (xi < Wl) && (yi >= 0) && (yi < Hl);
        int xc = xi < 0 ? 0 : (xi > Wl - 1 ? Wl - 1 : xi);
        int yc = yi < 0 ? 0 : (yi > Hl - 1 ? Hl - 1 : yi);
        short8 d = *(const short8*)(vb + (((size_t)(yc * Wl + xc)) << 8));
        float wg = valid ? wgt : 0.f;
#pragma unroll
        for (int i = 0; i < 8; ++i) acc[i] = fmaf(wg, bf2f((ushort)d[i]), acc[i]);
      };
      corner(x0, y0, w00);
      corner(x0 + 1, y0, w01);
      corner(x0, y0 + 1, w10);
      corner(x0 + 1, y0 + 1, w11);
    }
  }
  ushort o[8];
#pragma unroll
  for (int i = 0; i < 8; ++i) o[i] = f2bf(acc[i]);
  *(short8*)(samp + (bn << 8) + (lh << 3)) =
      (short8){(short)o[0], (short)o[1], (short)o[2], (short)o[3],
               (short)o[4], (short)o[5], (short)o[6], (short)o[7]};
}

// ---------------- final head: (B*N,256)@(256,7)+b, one wave per row ---------
__global__ void head_kernel(const float* __restrict__ hid, const float* __restrict__ W2,
                            const float* __restrict__ b2, float* __restrict__ outp) {
  int gid = blockIdx.x * 256 + threadIdx.x;
  int wave = gid >> 6;
  int lane = threadIdx.x & 63;
  if (wave >= kB * kN) return;
  const float* hrow = hid + ((size_t)wave << 8);
  float acc[kNCLS];
#pragma unroll
  for (int j = 0; j < kNCLS; ++j) acc[j] = 0.f;
  for (int k = lane; k < kC; k += 64) {
    float hv = hrow[k];
    const float* wr = W2 + k * kNCLS;
#pragma unroll
    for (int j = 0; j < kNCLS; ++j) acc[j] = fmaf(hv, wr[j], acc[j]);
  }
#pragma unroll
  for (int m = 32; m > 0; m >>= 1) {
#pragma unroll
    for (int j = 0; j < kNCLS; ++j) acc[j] += __shfl_xor(acc[j], m);
  }
  float r = 0.f;
#pragma unroll
  for (int j = 0; j < kNCLS; ++j)
    if (lane == j) r = acc[j] + b2[j];
  if (lane < kNCLS) outp[(size_t)wave * kNCLS + lane] = r;
}

}  // namespace

extern "C" void kernel_launch(void* const* d_in, const int* in_sizes, int n_in,
                              void* d_out, int out_size, void* d_ws, size_t ws_size,
                              hipStream_t stream) {
  const float* q_t    = (const float*)d_in[0];
  const float* h_t    = (const float*)d_in[1];
  const float* p_head = (const float*)d_in[2];
  const float* W_off  = (const float*)d_in[3];
  const float* b_off  = (const float*)d_in[4];
  const float* W_attn = (const float*)d_in[5];
  const float* b_attn = (const float*)d_in[6];
  const float* W_v    = (const float*)d_in[7];
  const float* b_v    = (const float*)d_in[8];
  const float* W_o    = (const float*)d_in[9];
  const float* b_o    = (const float*)d_in[10];
  const float* W_p1   = (const float*)d_in[11];
  const float* b_p1   = (const float*)d_in[12];
  const float* W_p2   = (const float*)d_in[13];
  const float* b_p2   = (const float*)d_in[14];
  float* out = (float*)d_out;
  char* wsb = (char*)d_ws;

  ushort* value = (ushort*)(wsb + 55705600);     // 55,705,600 (6800-stride)
  ushort* q_bf  = (ushort*)(wsb + 111411200);    //  8,388,608
  float*  offb  = (float*)(wsb + 119799808);     // 16,777,216
  float*  attnl = (float*)(wsb + 136577024);     //  8,388,608 (raw logits)
  ushort* samp  = (ushort*)(wsb + 144965632);    //  8,388,608
  ushort* qloc  = (ushort*)(wsb + 153354240);    //  8,388,608 (bf16)
  float*  hid   = (float*)(wsb + 161742848);     // 16,777,216
  ushort* wtp   = (ushort*)(wsb + 178520064);    //    720,896
  ushort* Wt_v  = wtp;                  // [256][256]
  ushort* Wt_oa = wtp + 65536;          // [384][256]
  ushort* Wt_o  = wtp + 163840;         // [256][256]
  ushort* Wt_p1 = wtp + 229376;         // [256][512]

  cast_f2b_kernel<<<4096, 256, 0, stream>>>(q_t, q_bf, kB * kN * 64);

  wtrans_all_kernel<<<dim3(8, 16, 5), 256, 0, stream>>>(
      W_v, W_off, W_attn, W_o, W_p1,
      Wt_v, Wt_oa, Wt_oa + 65536, Wt_o, Wt_p1);

  // value_L0 = h_t @ W_v + b_v  (M=81920 = 640*128; h_t read once, fp32)
  gemm_f32a_kernel<<<dim3(2, 640), 256, 0, stream>>>(h_t, Wt_v, b_v, value);

  // value pyramid by pooling the PROJECTED values (pool/proj commute)
  pool_b2b_kernel<<<20480, 256, 0, stream>>>(value, value, 32, 40, 0, 5120);
  pool_b2b_kernel<<<5120, 256, 0, stream>>>(value, value, 16, 20, 5120, 6400);
  pool_b2b_kernel<<<1280, 256, 0, stream>>>(value, value, 8, 10, 6400, 6720);

  gemm_bf16_kernel<256, false, 2, false><<<dim3(3, 128), 256, 0, stream>>>(
      q_bf, nullptr, Wt_oa, b_off, b_attn, offb, attnl, 256);

  deform_kernel<<<2048, 256, 0, stream>>>(value, offb, attnl, p_head, samp);

  gemm_bf16_kernel<256, false, 1, false><<<dim3(2, 128), 256, 0, stream>>>(
      samp, nullptr, Wt_o, b_o, nullptr, qloc, nullptr, 256);

  gemm_bf16_kernel<512, true, 0, true><<<dim3(2, 128), 256, 0, stream>>>(
      q_bf, qloc, Wt_p1, b_p1, nullptr, hid, nullptr, 256);

  head_kernel<<<4096, 256, 0, stream>>>(hid, W_p2, b_p2, out);
}